// Round 3
// baseline (341.374 us; speedup 1.0000x reference)
//
#include <hip/hip_runtime.h>
#include <hip/hip_bf16.h>

#define N_TOKENS 16384
#define DIM      2048
#define NEXP     64
#define TOPK     8
#define LOSCALE  2048.0f      // 2^11, exact power of two
#define NBLOCKS  1024         // 16 tokens per block
#define TOKPB    16
#define NWAVES   4            // waves per block, K-split
#define KSLAB    512          // K per wave
#define NCHUNK   16           // KSLAB / 32
#define LSTRIDE  66           // LDS token stride: (264*quad+row16)%32 -> <=2-way
#define NREP     32           // replicated aux accumulators

typedef _Float16 half8   __attribute__((ext_vector_type(8)));
typedef float    floatx4 __attribute__((ext_vector_type(4)));

// ---------------------------------------------------------------------------
// Kernel 0: split W (64x2048 fp32) into f16 hi/lo planes.
//   whi = (f16)w;  wlo = (f16)((w - (f32)whi) * 2^11)
// ---------------------------------------------------------------------------
__global__ __launch_bounds__(256) void wprep_kernel(const float* __restrict__ W,
                                                    _Float16* __restrict__ Whi,
                                                    _Float16* __restrict__ Wlo) {
    int i = blockIdx.x * 256 + threadIdx.x;           // grid 512 -> 131072
    float w = W[i];
    _Float16 h = (_Float16)w;
    Whi[i] = h;
    Wlo[i] = (_Float16)((w - (float)h) * LOSCALE);
}

// ---------------------------------------------------------------------------
// Fused kernel: MFMA router GEMM + softmax + top-8 + aux partials + (last
// block) aux finalize. Logits never touch HBM.
//   - 1024 blocks x 4 waves; block owns 16 tokens; waves K-split (512 k).
//     Occupancy comes from the GRID (4 blocks/CU = 16 waves/CU resident),
//     NOT from __launch_bounds__ arg2: R1 (arg2=4 -> 64-VGPR cap -> 95 MB
//     spills) and R2 (arg2=2 -> pressure-aware scheduling sank the prefetch
//     loads, VGPR 116->84, pipeline destroyed, 161us) both showed arg2
//     breaks the hand-written software pipeline on this toolchain.
//     This keeps R0's proven codegen shape (256 threads, prefetch depth 1),
//     with the mt dimension removed: acc 64->32 VGPRs, LDS 16.9 KB/block.
//   - K-loop: f16-split MFMA (a ~ ah + al/2^11; dropped ll term ~2^-22|a||b|,
//     validated index-exact previously). No LDS/barriers in loop; next
//     chunk's loads issued before current MFMAs.
//   - Exchange: partial logits -> LDS [wave][tok][exp], token stride 66
//     (writes/reads <=2-way bank aliasing = free). One barrier.
//   - Epilogue: wave w does softmax + rank-select for tokens [4w,4w+4);
//     rank_i = #{j: s_j>s_i or (s_j==s_i and j<i)} = lax.top_k semantics.
//   - aux: per-lane cnt/sp -> LDS reduce -> global atomics into replica
//     blockIdx&31; last block (ticket) sums replicas and writes aux_loss.
// ---------------------------------------------------------------------------
__global__ __launch_bounds__(256) void moe_kernel(const float* __restrict__ A,
                                                  const _Float16* __restrict__ Whi,
                                                  const _Float16* __restrict__ Wlo,
                                                  float* __restrict__ out_w,
                                                  float* __restrict__ out_i,
                                                  float* __restrict__ out_aux,
                                                  float* __restrict__ cnt_ws,
                                                  float* __restrict__ sp_ws,
                                                  unsigned int* __restrict__ ticket) {
    __shared__ float lds[NWAVES * TOKPB * LSTRIDE];   // 16.9 KB
    __shared__ float s_cnt[NEXP];
    __shared__ float s_sp[NEXP];
    __shared__ int   s_last;

    const int lane  = threadIdx.x & 63;
    const int wv    = threadIdx.x >> 6;      // k-slab 0..3
    const int row16 = lane & 15;
    const int quad  = lane >> 4;
    const int tbase = blockIdx.x * TOKPB;
    const int kbase = wv * KSLAB;

    if (threadIdx.x < NEXP) { s_cnt[threadIdx.x] = 0.f; s_sp[threadIdx.x] = 0.f; }

    floatx4 acc0[4] = {};   // hi*hi
    floatx4 acc1[4] = {};   // hi*lo_s + lo_s*hi (carries 2^11)

    const float* ap0 = A + (size_t)(tbase + row16) * DIM + quad * 8;
    const size_t boff = (size_t)row16 * DIM + quad * 8;

    // prologue loads (chunk 0)
    float4 ar[2];
    half8  bh[4], bl[4];
    ar[0] = *(const float4*)(ap0 + kbase);
    ar[1] = *(const float4*)(ap0 + kbase + 4);
    #pragma unroll
    for (int nt = 0; nt < 4; ++nt) {
        bh[nt] = *(const half8*)(Whi + (size_t)nt * 16 * DIM + boff + kbase);
        bl[nt] = *(const half8*)(Wlo + (size_t)nt * 16 * DIM + boff + kbase);
    }

    for (int it = 0; it < NCHUNK; ++it) {
        // issue next chunk's loads first; they fly during split + MFMA
        float4 arn[2];
        half8  bhn[4], bln[4];
        if (it < NCHUNK - 1) {
            int kc = kbase + (it + 1) * 32;
            arn[0] = *(const float4*)(ap0 + kc);
            arn[1] = *(const float4*)(ap0 + kc + 4);
            #pragma unroll
            for (int nt = 0; nt < 4; ++nt) {
                bhn[nt] = *(const half8*)(Whi + (size_t)nt * 16 * DIM + boff + kc);
                bln[nt] = *(const half8*)(Wlo + (size_t)nt * 16 * DIM + boff + kc);
            }
        }

        // split current A f32 -> f16 hi/lo
        half8 ah, al;
        {
            float av[8] = {ar[0].x, ar[0].y, ar[0].z, ar[0].w,
                           ar[1].x, ar[1].y, ar[1].z, ar[1].w};
            #pragma unroll
            for (int j = 0; j < 8; ++j) {
                _Float16 h = (_Float16)av[j];
                ah[j] = h;
                al[j] = (_Float16)((av[j] - (float)h) * LOSCALE);
            }
        }

        #pragma unroll
        for (int nt = 0; nt < 4; ++nt) {
            acc0[nt] = __builtin_amdgcn_mfma_f32_16x16x32_f16(ah, bh[nt], acc0[nt], 0, 0, 0);
            acc1[nt] = __builtin_amdgcn_mfma_f32_16x16x32_f16(ah, bl[nt], acc1[nt], 0, 0, 0);
            acc1[nt] = __builtin_amdgcn_mfma_f32_16x16x32_f16(al, bh[nt], acc1[nt], 0, 0, 0);
        }

        ar[0] = arn[0]; ar[1] = arn[1];
        #pragma unroll
        for (int nt = 0; nt < 4; ++nt) { bh[nt] = bhn[nt]; bl[nt] = bln[nt]; }
    }

    // partial logits -> LDS ; C layout: col=lane&15 (expert), row=quad*4+reg
    const float inv = 1.0f / LOSCALE;
    #pragma unroll
    for (int nt = 0; nt < 4; ++nt)
        #pragma unroll
        for (int reg = 0; reg < 4; ++reg) {
            int tok = quad * 4 + reg;
            lds[(wv * TOKPB + tok) * LSTRIDE + nt * 16 + row16] =
                acc0[nt][reg] + acc1[nt][reg] * inv;
        }
    __syncthreads();

    // epilogue: wave wv handles tokens [wv*4, wv*4+4); lane = expert
    float sp = 0.f, cnt = 0.f;
    for (int i = 0; i < 4; ++i) {
        int t = wv * 4 + i;
        float lg = (lds[t * LSTRIDE + lane]                   + lds[(TOKPB + t) * LSTRIDE + lane])
                 + (lds[(2 * TOKPB + t) * LSTRIDE + lane]     + lds[(3 * TOKPB + t) * LSTRIDE + lane]);

        float m = lg;
        #pragma unroll
        for (int off = 32; off; off >>= 1) m = fmaxf(m, __shfl_xor(m, off));
        float e = expf(lg - m);
        float ssum = e;
        #pragma unroll
        for (int off = 32; off; off >>= 1) ssum += __shfl_xor(ssum, off);
        float score = e / ssum;
        sp += score;

        int rank = 0;
        #pragma unroll
        for (int j = 0; j < 64; ++j) {
            float sj = __shfl(score, j);
            rank += (sj > score) || (sj == score && j < lane);
        }
        bool sel = rank < TOPK;

        float v = sel ? score : 0.f;
        #pragma unroll
        for (int off = 32; off; off >>= 1) v += __shfl_xor(v, off);

        if (sel) {
            out_w[(size_t)(tbase + t) * TOPK + rank] = score / v;
            out_i[(size_t)(tbase + t) * TOPK + rank] = (float)lane;
            cnt += 1.f;
        }
    }

    atomicAdd(&s_sp[lane], sp);
    atomicAdd(&s_cnt[lane], cnt);
    __syncthreads();
    const int rep = (blockIdx.x & (NREP - 1)) * NEXP;
    if (threadIdx.x < 64)       atomicAdd(&cnt_ws[rep + threadIdx.x], s_cnt[threadIdx.x]);
    else if (threadIdx.x < 128) atomicAdd(&sp_ws[rep + threadIdx.x - 64], s_sp[threadIdx.x - 64]);

    // release our atomics, then take a ticket; last block finalizes
    __threadfence();
    __syncthreads();
    if (threadIdx.x == 0)
        s_last = (atomicAdd(ticket, 1u) == (unsigned)(gridDim.x - 1));
    __syncthreads();
    if (s_last && threadIdx.x < 64) {
        float c = 0.f, p = 0.f;
        #pragma unroll
        for (int r = 0; r < NREP; ++r) {
            c += atomicAdd(&cnt_ws[r * NEXP + threadIdx.x], 0.f);   // device-scope read
            p += atomicAdd(&sp_ws [r * NEXP + threadIdx.x], 0.f);
        }
        float v = (c / (float)(N_TOKENS * TOPK)) * (p / (float)N_TOKENS);
        #pragma unroll
        for (int off = 32; off; off >>= 1) v += __shfl_xor(v, off);
        if (threadIdx.x == 0) out_aux[0] = 0.001f * (float)NEXP * v;
    }
}

extern "C" void kernel_launch(void* const* d_in, const int* in_sizes, int n_in,
                              void* d_out, int out_size, void* d_ws, size_t ws_size,
                              hipStream_t stream) {
    const float* A = (const float*)d_in[0];   // hidden_states (16384 x 2048)
    const float* W = (const float*)d_in[1];   // weight        (64 x 2048)
    float* out = (float*)d_out;

    _Float16*     whi    = (_Float16*)d_ws;
    _Float16*     wlo    = whi + (size_t)NEXP * DIM;
    float*        cnt_ws = (float*)(wlo + (size_t)NEXP * DIM);
    float*        sp_ws  = cnt_ws + (size_t)NREP * NEXP;
    unsigned int* ticket = (unsigned int*)(sp_ws + (size_t)NREP * NEXP);

    // zero cnt(8KB) + sp(8KB) + ticket(4B)
    hipMemsetAsync(cnt_ws, 0, 2 * NREP * NEXP * sizeof(float) + sizeof(unsigned int), stream);

    hipLaunchKernelGGL(wprep_kernel, dim3(NEXP * DIM / 256), dim3(256), 0, stream,
                       W, whi, wlo);

    float* out_w = out;
    float* out_i = out + (size_t)N_TOKENS * TOPK;
    float* out_a = out + 2 * (size_t)N_TOKENS * TOPK;

    hipLaunchKernelGGL(moe_kernel, dim3(NBLOCKS), dim3(256), 0, stream,
                       A, whi, wlo, out_w, out_i, out_a, cnt_ws, sp_ws, ticket);
}

// Round 5
// 247.009 us; speedup vs baseline: 1.3820x; 1.3820x over previous
//
#include <hip/hip_runtime.h>
#include <hip/hip_bf16.h>

#define N_TOKENS 16384
#define DIM      2048
#define NEXP     64
#define TOPK     8
#define LOSCALE  2048.0f      // 2^11, exact power of two
#define NBLOCKS  512          // 32 tokens per block
#define TOKPB    32
#define LSTRIDE  66           // exchange stride: <=2-way bank aliasing
#define NREP     32           // replicated aux accumulators
#define NCHUNKS  64           // K chunks of 32 (full K per wave)
#define NROUNDS  16           // K rounds of 128 (4 chunks per round)
#define SROW     264          // stage row stride in halves (528 B)

typedef _Float16 half8   __attribute__((ext_vector_type(8)));
typedef float    floatx4 __attribute__((ext_vector_type(4)));

// ---------------------------------------------------------------------------
// Kernel 0: split W (64x2048 fp32) into f16 hi/lo planes.
//   whi = (f16)w;  wlo = (f16)((w - (f32)whi) * 2^11)
// ---------------------------------------------------------------------------
__global__ __launch_bounds__(256) void wprep_kernel(const float* __restrict__ W,
                                                    _Float16* __restrict__ Whi,
                                                    _Float16* __restrict__ Wlo) {
    int i = blockIdx.x * 256 + threadIdx.x;           // grid 512 -> 131072
    float w = W[i];
    _Float16 h = (_Float16)w;
    Whi[i] = h;
    Wlo[i] = (_Float16)((w - (float)h) * LOSCALE);
}

// split 8 floats (two float4) -> f16 hi/lo half8 pair
__device__ __forceinline__ void split2x8(const float4& f0, const float4& f1,
                                         half8& H, half8& L) {
    float v[8] = {f0.x, f0.y, f0.z, f0.w, f1.x, f1.y, f1.z, f1.w};
    #pragma unroll
    for (int j = 0; j < 8; ++j) {
        _Float16 h = (_Float16)v[j];
        H[j] = h;
        L[j] = (_Float16)((v[j] - (float)h) * LOSCALE);
    }
}

// stage 16 floats (this thread's 64B segment) into the stage buffer,
// packed as [hi8|lo8|hi8|lo8] (4 x 16B writes)
__device__ __forceinline__ void split_write(_Float16* sw,
                                            const float4& f0, const float4& f1,
                                            const float4& f2, const float4& f3) {
    half8 h, l;
    split2x8(f0, f1, h, l);
    *(half8*)(sw)      = h;
    *(half8*)(sw + 8)  = l;
    split2x8(f2, f3, h, l);
    *(half8*)(sw + 16) = h;
    *(half8*)(sw + 24) = l;
}

// ---------------------------------------------------------------------------
// Canonical staged MoE router kernel. 512 blocks x 4 waves; block = 32 tokens.
//
// Theory (R0-R3 evidence): the old K-split/direct-load loop had ~13 lines/CU
// in flight (Little's law at 1.16 TB/s) -- the arn->ar register copies forced
// vmcnt(0) every chunk (prefetch depth 1), and the 64-VGPR accumulator made
// deeper prefetch spill (R1). More waves made it WORSE 3x in a row (R2/R3):
// not a TLP problem, an MLP/structure problem. This kernel:
//   - waves split EXPERTS (16 each, full K): acc = 16 VGPRs, B = 2 loads/chunk
//   - A staged via LDS per 128-k round: coalesced f32 loads, split f32->f16
//     hi/lo ONCE per element by the stager, double-buffered; next round's
//     global loads issued before this round's MFMAs (~400cy hiding)
//   - B prefetched depth 4 in named register sets (no runtime indexing)
//   - stage layout [32][264] halves (528B row stride): b128 reads/writes get
//     even 8-slot bank spread; groups packed [hi8|lo8] (32 B)
//   - epilogue: single-plane exchange (each (tok,expert) written once), then
//     R0's validated softmax + rank-select (lax.top_k semantics) + aux.
// ---------------------------------------------------------------------------
__global__ __launch_bounds__(256) void moe_kernel(const float* __restrict__ A,
                                                  const _Float16* __restrict__ Whi,
                                                  const _Float16* __restrict__ Wlo,
                                                  float* __restrict__ out_w,
                                                  float* __restrict__ out_i,
                                                  float* __restrict__ out_aux,
                                                  float* __restrict__ cnt_ws,
                                                  float* __restrict__ sp_ws,
                                                  unsigned int* __restrict__ ticket) {
    __shared__ _Float16 stage[2][TOKPB][SROW];     // 2 x 32 x 264 x 2B = 33 KB
    __shared__ float    xch[TOKPB * LSTRIDE];      // 8.4 KB
    __shared__ float    s_cnt[NEXP];
    __shared__ float    s_sp[NEXP];
    __shared__ int      s_last;

    const int tid   = threadIdx.x;
    const int lane  = tid & 63;
    const int wv    = tid >> 6;          // expert tile 0..3
    const int row16 = lane & 15;
    const int quad  = lane >> 4;
    const int tbase = blockIdx.x * TOKPB;

    if (tid < NEXP) { s_cnt[tid] = 0.f; s_sp[tid] = 0.f; }

    // ---- stager role: thread covers token row (tid>>3), 64B seg (tid&7) ----
    const int srow = tid >> 3;
    const int sseg = tid & 7;
    const float* Ap = A + (size_t)(tbase + srow) * DIM + sseg * 16;
    _Float16* sw0 = &stage[0][0][0] + srow * SROW + (2 * sseg) * 16;
    _Float16* sw1 = &stage[1][0][0] + srow * SROW + (2 * sseg) * 16;

    // ---- MFMA role: wave wv's expert rows ----
    const _Float16* bhp = Whi + (size_t)(wv * 16 + row16) * DIM + quad * 8;
    const _Float16* blp = Wlo + (size_t)(wv * 16 + row16) * DIM + quad * 8;

    floatx4 acc0[2] = {};   // hi*hi         (mt = 0,1)
    floatx4 acc1[2] = {};   // hi*lo + lo*hi (carries 2^11)

    // one k=32 chunk: read A frags from staged buffer, 6 MFMAs with B set
#define BODY(I_, BH_, BL_)                                                    \
    do {                                                                      \
        int _off = row16 * SROW + ((I_) * 4 + quad) * 16;                     \
        half8 _a0 = *(const half8*)(sb + _off);                               \
        half8 _l0 = *(const half8*)(sb + _off + 8);                           \
        half8 _a1 = *(const half8*)(sb + _off + 16 * SROW);                   \
        half8 _l1 = *(const half8*)(sb + _off + 16 * SROW + 8);               \
        acc0[0] = __builtin_amdgcn_mfma_f32_16x16x32_f16(_a0, BH_, acc0[0], 0, 0, 0); \
        acc1[0] = __builtin_amdgcn_mfma_f32_16x16x32_f16(_a0, BL_, acc1[0], 0, 0, 0); \
        acc1[0] = __builtin_amdgcn_mfma_f32_16x16x32_f16(_l0, BH_, acc1[0], 0, 0, 0); \
        acc0[1] = __builtin_amdgcn_mfma_f32_16x16x32_f16(_a1, BH_, acc0[1], 0, 0, 0); \
        acc1[1] = __builtin_amdgcn_mfma_f32_16x16x32_f16(_a1, BL_, acc1[1], 0, 0, 0); \
        acc1[1] = __builtin_amdgcn_mfma_f32_16x16x32_f16(_l1, BH_, acc1[1], 0, 0, 0); \
    } while (0)

    // ---- prologue: B chunks 0..3 in flight; stage round 0 ----
    half8 b0h = *(const half8*)(bhp + 0 * 32), b0l = *(const half8*)(blp + 0 * 32);
    half8 b1h = *(const half8*)(bhp + 1 * 32), b1l = *(const half8*)(blp + 1 * 32);
    half8 b2h = *(const half8*)(bhp + 2 * 32), b2l = *(const half8*)(blp + 2 * 32);
    half8 b3h = *(const half8*)(bhp + 3 * 32), b3l = *(const half8*)(blp + 3 * 32);

    {
        float4 f0 = *(const float4*)(Ap + 0);
        float4 f1 = *(const float4*)(Ap + 4);
        float4 f2 = *(const float4*)(Ap + 8);
        float4 f3 = *(const float4*)(Ap + 12);
        split_write(sw0, f0, f1, f2, f3);
    }
    __syncthreads();

    // ---- main loop: 16 rounds x 4 chunks ----
    for (int r = 0; r < NROUNDS; ++r) {
        float4 g0, g1, g2, g3;
        if (r < NROUNDS - 1) {                       // issue next round's A loads NOW
            const float* p = Ap + (r + 1) * 128;
            g0 = *(const float4*)(p);
            g1 = *(const float4*)(p + 4);
            g2 = *(const float4*)(p + 8);
            g3 = *(const float4*)(p + 12);
        }
        const _Float16* sb = &stage[r & 1][0][0];
        const int c = 4 * r;

        BODY(0, b0h, b0l);
        if (c + 4 < NCHUNKS) { b0h = *(const half8*)(bhp + (c + 4) * 32); b0l = *(const half8*)(blp + (c + 4) * 32); }
        BODY(1, b1h, b1l);
        if (c + 5 < NCHUNKS) { b1h = *(const half8*)(bhp + (c + 5) * 32); b1l = *(const half8*)(blp + (c + 5) * 32); }
        BODY(2, b2h, b2l);
        if (c + 6 < NCHUNKS) { b2h = *(const half8*)(bhp + (c + 6) * 32); b2l = *(const half8*)(blp + (c + 6) * 32); }
        BODY(3, b3h, b3l);
        if (c + 7 < NCHUNKS) { b3h = *(const half8*)(bhp + (c + 7) * 32); b3l = *(const half8*)(blp + (c + 7) * 32); }

        if (r < NROUNDS - 1) split_write((r & 1) ? sw0 : sw1, g0, g1, g2, g3);
        __syncthreads();
    }

    // ---- exchange: single plane; C layout col=lane&15(expert sub), row=quad*4+reg ----
    const float inv = 1.0f / LOSCALE;
    #pragma unroll
    for (int mt = 0; mt < 2; ++mt)
        #pragma unroll
        for (int reg = 0; reg < 4; ++reg) {
            int tok = mt * 16 + quad * 4 + reg;
            xch[tok * LSTRIDE + wv * 16 + row16] = acc0[mt][reg] + acc1[mt][reg] * inv;
        }
    __syncthreads();

    // ---- epilogue: wave wv handles tokens [wv*8, wv*8+8); lane = expert ----
    float sp = 0.f, cnt = 0.f;
    for (int i = 0; i < 8; ++i) {
        int t = wv * 8 + i;
        float lg = xch[t * LSTRIDE + lane];

        float m = lg;
        #pragma unroll
        for (int off = 32; off; off >>= 1) m = fmaxf(m, __shfl_xor(m, off));
        float e = expf(lg - m);
        float ssum = e;
        #pragma unroll
        for (int off = 32; off; off >>= 1) ssum += __shfl_xor(ssum, off);
        float score = e / ssum;
        sp += score;

        int rank = 0;
        #pragma unroll
        for (int j = 0; j < 64; ++j) {
            float sj = __shfl(score, j);
            rank += (sj > score) || (sj == score && j < lane);
        }
        bool sel = rank < TOPK;

        float v = sel ? score : 0.f;
        #pragma unroll
        for (int off = 32; off; off >>= 1) v += __shfl_xor(v, off);

        if (sel) {
            out_w[(size_t)(tbase + t) * TOPK + rank] = score / v;
            out_i[(size_t)(tbase + t) * TOPK + rank] = (float)lane;
            cnt += 1.f;
        }
    }

    atomicAdd(&s_sp[lane], sp);
    atomicAdd(&s_cnt[lane], cnt);
    __syncthreads();
    const int rep = (blockIdx.x & (NREP - 1)) * NEXP;
    if (tid < 64)       atomicAdd(&cnt_ws[rep + tid], s_cnt[tid]);
    else if (tid < 128) atomicAdd(&sp_ws[rep + tid - 64], s_sp[tid - 64]);

    // release our atomics, then take a ticket; last block finalizes
    __threadfence();
    __syncthreads();
    if (tid == 0)
        s_last = (atomicAdd(ticket, 1u) == (unsigned)(gridDim.x - 1));
    __syncthreads();
    if (s_last && tid < 64) {
        float c = 0.f, p = 0.f;
        #pragma unroll
        for (int rr = 0; rr < NREP; ++rr) {
            c += atomicAdd(&cnt_ws[rr * NEXP + tid], 0.f);   // device-scope read
            p += atomicAdd(&sp_ws [rr * NEXP + tid], 0.f);
        }
        float v = (c / (float)(N_TOKENS * TOPK)) * (p / (float)N_TOKENS);
        #pragma unroll
        for (int off = 32; off; off >>= 1) v += __shfl_xor(v, off);
        if (tid == 0) out_aux[0] = 0.001f * (float)NEXP * v;
    }
}

extern "C" void kernel_launch(void* const* d_in, const int* in_sizes, int n_in,
                              void* d_out, int out_size, void* d_ws, size_t ws_size,
                              hipStream_t stream) {
    const float* A = (const float*)d_in[0];   // hidden_states (16384 x 2048)
    const float* W = (const float*)d_in[1];   // weight        (64 x 2048)
    float* out = (float*)d_out;

    _Float16*     whi    = (_Float16*)d_ws;
    _Float16*     wlo    = whi + (size_t)NEXP * DIM;
    float*        cnt_ws = (float*)(wlo + (size_t)NEXP * DIM);
    float*        sp_ws  = cnt_ws + (size_t)NREP * NEXP;
    unsigned int* ticket = (unsigned int*)(sp_ws + (size_t)NREP * NEXP);

    // zero cnt(8KB) + sp(8KB) + ticket(4B)
    hipMemsetAsync(cnt_ws, 0, 2 * NREP * NEXP * sizeof(float) + sizeof(unsigned int), stream);

    hipLaunchKernelGGL(wprep_kernel, dim3(NEXP * DIM / 256), dim3(256), 0, stream,
                       W, whi, wlo);

    float* out_w = out;
    float* out_i = out + (size_t)N_TOKENS * TOPK;
    float* out_a = out + 2 * (size_t)N_TOKENS * TOPK;

    hipLaunchKernelGGL(moe_kernel, dim3(NBLOCKS), dim3(256), 0, stream,
                       A, whi, wlo, out_w, out_i, out_a, cnt_ws, sp_ws, ticket);
}